// Round 1
// baseline (484.111 us; speedup 1.0000x reference)
//
#include <hip/hip_runtime.h>
#include <hip/hip_bf16.h>

// WindowAttention fused kernel for MI355X (gfx950).
// Strategy: 1 block = 1 window (2048 blocks x 256 threads = 4 waves).
//  - stage concat(x,y) as bf16 in LDS (XOR-swizzled, rows padded 49->64 with zeros)
//  - per head h: QKV GEMM (64x192x384, bf16 MFMA 16x16x32, weights streamed from L2),
//    S = Q K^T via MFMA, add precomputed (rpb[h] + mask[w]) table (pad cols = -1e30),
//    in-register softmax (shfl_xor butterfly over 16-lane groups), P -> LDS bf16,
//    O = P V via MFMA (V stored transposed), normalize, accumulate into attnout LDS.
//  - proj GEMM (64x192x384) from attnout LDS, + b_proj, store f32 rows < 49.
// ws usage (~7.3 MB): bf16 w_qkv, bf16 w_proj, combined bias+mask table [64][6][64][64] f32.

typedef __attribute__((ext_vector_type(8))) short short8;
typedef __attribute__((ext_vector_type(4))) float f32x4;

#define SCALE 0.17677669529663687f  // (192/6)^-0.5

#define WQ_ELEMS (1152*384)
#define WP_ELEMS (192*384)
#define WP_OFF   (WQ_ELEMS*2)              // bytes into ws
#define COMB_OFF (WP_OFF + WP_ELEMS*2)     // bytes into ws

__device__ __forceinline__ unsigned short f2bf(float f){
  unsigned u = __builtin_bit_cast(unsigned, f);
  u = u + 0x7fffu + ((u >> 16) & 1u);      // round-to-nearest-even
  return (unsigned short)(u >> 16);
}

__device__ __forceinline__ unsigned long long pack4(float4 v){
  return (unsigned long long)f2bf(v.x) | ((unsigned long long)f2bf(v.y) << 16)
       | ((unsigned long long)f2bf(v.z) << 32) | ((unsigned long long)f2bf(v.w) << 48);
}

// ---------------- prep kernels ----------------

__global__ void prep_weights(const float* __restrict__ wq_f, const float* __restrict__ wp_f,
                             unsigned short* __restrict__ wq, unsigned short* __restrict__ wp){
  int gid = blockIdx.x * 256 + threadIdx.x;
  if (gid < WQ_ELEMS) {
    wq[gid] = f2bf(wq_f[gid]);
  } else {
    int g = gid - WQ_ELEMS;
    if (g < WP_ELEMS) wp[g] = f2bf(wp_f[g]);
  }
}

// comb[w][h][i][j] (i,j in [0,64)) = rpb[h][i][j] + mask[w][i][j] for valid i,j<49,
// else -1e30 for pad cols j>=49 (so exp -> 0), 0 otherwise.
__global__ void prep_comb(const float* __restrict__ mask, const float* __restrict__ btab,
                          float* __restrict__ comb){
  int idx = blockIdx.x * 256 + threadIdx.x;          // < 64*6*4096
  int j = idx & 63, i = (idx >> 6) & 63, rest = idx >> 12;
  int h = rest % 6, w = rest / 6;
  float v;
  if (i < 49 && j < 49){
    int di = i / 7 - j / 7 + 6;
    int dj = i % 7 - j % 7 + 6;
    v = btab[(di * 13 + dj) * 6 + h] + mask[(w * 49 + i) * 49 + j];
  } else {
    v = (j >= 49) ? -1e30f : 0.0f;
  }
  comb[idx] = v;
}

// ---------------- fused main kernel ----------------

// LDS byte offsets (total 131072):
//   xy      [64][384] bf16 @ 0       (stride 768 B)
//   attnout [64][384] bf16 @ 49152   (stride 768 B)
//   q       [64][64]  bf16 @ 98304   (stride 128 B)
//   k       [64][64]  bf16 @ 106496
//   vt      [64][64]  bf16 @ 114688  (transposed: [d][token])
//   p       [64][64]  bf16 @ 122880
__device__ __forceinline__ int swz(int r, int b){ return b ^ ((r & 7) << 4); }
__device__ __forceinline__ int a_xy(int r, int c){ return 0      + swz(r, r*768 + c*2); }
__device__ __forceinline__ int a_ao(int r, int c){ return 49152  + swz(r, r*768 + c*2); }
__device__ __forceinline__ int a_q (int r, int c){ return 98304  + swz(r, r*128 + c*2); }
__device__ __forceinline__ int a_k (int r, int c){ return 106496 + swz(r, r*128 + c*2); }
__device__ __forceinline__ int a_vt(int r, int c){ return 114688 + swz(r, r*128 + c*2); }
__device__ __forceinline__ int a_p (int r, int c){ return 122880 + swz(r, r*128 + c*2); }

__global__ __launch_bounds__(256, 1)
void fused_attn(const float* __restrict__ x, const float* __restrict__ y,
                const float* __restrict__ bqkv, const float* __restrict__ bproj,
                const unsigned short* __restrict__ wq, const unsigned short* __restrict__ wp,
                const float* __restrict__ comb, float* __restrict__ out){
  __shared__ __align__(16) unsigned char smem[131072];
  const int b   = blockIdx.x;
  const int tid = threadIdx.x;
  const int w   = tid >> 6;        // wave 0..3
  const int l   = tid & 63;
  const int l15 = l & 15;
  const int lg  = l >> 4;          // lane group 0..3

  // ---- stage concat(x,y) -> bf16 LDS, zero-pad rows 49..63 ----
  {
    const float4* x4 = (const float4*)x + b * 2352;   // 49*192/4
    const float4* y4 = (const float4*)y + b * 2352;
    for (int idx = tid; idx < 2352; idx += 256){
      int r = idx / 48, c4 = (idx % 48) * 4;
      float4 vx = x4[idx];
      float4 vy = y4[idx];
      *(unsigned long long*)(smem + a_xy(r, c4))       = pack4(vx);
      *(unsigned long long*)(smem + a_xy(r, 192 + c4)) = pack4(vy);
    }
    for (int idx = tid; idx < 1440; idx += 256){       // 15 rows * 96 chunks of 4
      int r = 49 + idx / 96, c4 = (idx % 96) * 4;
      *(unsigned long long*)(smem + a_xy(r, c4)) = 0ull;
    }
  }
  __syncthreads();

  const float* cbB = comb + (long)(b & 63) * (6 * 4096);

  #pragma unroll 1
  for (int h = 0; h < 6; ++h){
    // ---- QKV GEMM: this wave owns output cols [w*48, w*48+48) of 192 (q|k|v x 64) ----
    f32x4 acc[4][3] = {};
    int   wrow[3];
    float bias[3];
    #pragma unroll
    for (int nt = 0; nt < 3; ++nt){
      int n = w * 48 + nt * 16 + l15;
      wrow[nt] = (n >> 6) * 384 + h * 64 + (n & 63);   // row of w_qkv
      bias[nt] = bqkv[wrow[nt]];
    }
    #pragma unroll 4
    for (int kt = 0; kt < 12; ++kt){
      int k0 = kt * 32;
      short8 a[4];
      #pragma unroll
      for (int mt = 0; mt < 4; ++mt)
        a[mt] = *(const short8*)(smem + a_xy(mt * 16 + l15, k0 + lg * 8));
      #pragma unroll
      for (int nt = 0; nt < 3; ++nt){
        short8 bb = *(const short8*)(wq + (long)wrow[nt] * 384 + k0 + lg * 8);
        #pragma unroll
        for (int mt = 0; mt < 4; ++mt)
          acc[mt][nt] = __builtin_amdgcn_mfma_f32_16x16x32_bf16(a[mt], bb, acc[mt][nt], 0, 0, 0);
      }
    }
    // epilogue: scatter to q / k / vt (transposed) LDS as bf16
    #pragma unroll
    for (int nt = 0; nt < 3; ++nt){
      int n = w * 48 + nt * 16 + l15;
      int s = n >> 6, d = n & 63;
      #pragma unroll
      for (int mt = 0; mt < 4; ++mt){
        #pragma unroll
        for (int j = 0; j < 4; ++j){
          int row = mt * 16 + lg * 4 + j;
          float v = acc[mt][nt][j] + bias[nt];
          if (s == 0) v *= SCALE;
          int addr = (s == 0) ? a_q(row, d) : (s == 1) ? a_k(row, d) : a_vt(d, row);
          *(unsigned short*)(smem + addr) = f2bf(v);
        }
      }
    }
    __syncthreads();

    // ---- attention: wave w owns query rows [w*16, w*16+16) ----
    short8 aq[2];
    #pragma unroll
    for (int ks = 0; ks < 2; ++ks)
      aq[ks] = *(const short8*)(smem + a_q(w * 16 + l15, ks * 32 + lg * 8));
    f32x4 sacc[4] = {};
    #pragma unroll
    for (int ks = 0; ks < 2; ++ks){
      #pragma unroll
      for (int nt = 0; nt < 4; ++nt){
        short8 bk = *(const short8*)(smem + a_k(nt * 16 + l15, ks * 32 + lg * 8));
        sacc[nt] = __builtin_amdgcn_mfma_f32_16x16x32_bf16(aq[ks], bk, sacc[nt], 0, 0, 0);
      }
    }
    // + (rpb + mask) table, softmax along 64 cols (pad cols hold -1e30)
    const float* cb = cbB + h * 4096;
    float rs[4];
    #pragma unroll
    for (int j = 0; j < 4; ++j){
      int r = w * 16 + lg * 4 + j;
      #pragma unroll
      for (int nt = 0; nt < 4; ++nt)
        sacc[nt][j] += cb[r * 64 + nt * 16 + l15];
      float m = fmaxf(fmaxf(sacc[0][j], sacc[1][j]), fmaxf(sacc[2][j], sacc[3][j]));
      #pragma unroll
      for (int dlt = 1; dlt < 16; dlt <<= 1) m = fmaxf(m, __shfl_xor(m, dlt));
      float ssum = 0.f;
      #pragma unroll
      for (int nt = 0; nt < 4; ++nt){
        float e = __expf(sacc[nt][j] - m);
        sacc[nt][j] = e;
        ssum += e;
      }
      #pragma unroll
      for (int dlt = 1; dlt < 16; dlt <<= 1) ssum += __shfl_xor(ssum, dlt);
      rs[j] = ssum;
      #pragma unroll
      for (int nt = 0; nt < 4; ++nt)
        *(unsigned short*)(smem + a_p(r, nt * 16 + l15)) = f2bf(sacc[nt][j]);
    }
    // PV: same-wave LDS dependency only (lgkmcnt wait, no barrier needed)
    short8 ap[2];
    #pragma unroll
    for (int ks = 0; ks < 2; ++ks)
      ap[ks] = *(const short8*)(smem + a_p(w * 16 + l15, ks * 32 + lg * 8));
    f32x4 oacc[4] = {};
    #pragma unroll
    for (int ks = 0; ks < 2; ++ks){
      #pragma unroll
      for (int nt = 0; nt < 4; ++nt){
        short8 bv = *(const short8*)(smem + a_vt(nt * 16 + l15, ks * 32 + lg * 8));
        oacc[nt] = __builtin_amdgcn_mfma_f32_16x16x32_bf16(ap[ks], bv, oacc[nt], 0, 0, 0);
      }
    }
    float inv[4];
    #pragma unroll
    for (int j = 0; j < 4; ++j) inv[j] = 1.0f / rs[j];
    #pragma unroll
    for (int nt = 0; nt < 4; ++nt){
      #pragma unroll
      for (int j = 0; j < 4; ++j){
        int row = w * 16 + lg * 4 + j;
        *(unsigned short*)(smem + a_ao(row, h * 64 + nt * 16 + l15)) = f2bf(oacc[nt][j] * inv[j]);
      }
    }
    __syncthreads();
  }

  // ---- proj GEMM: wave owns output cols [w*48, w*48+48) of 192 ----
  f32x4 pacc[4][3] = {};
  int   np[3];
  float bp[3];
  #pragma unroll
  for (int nt = 0; nt < 3; ++nt){
    np[nt] = w * 48 + nt * 16 + l15;
    bp[nt] = bproj[np[nt]];
  }
  #pragma unroll 4
  for (int kt = 0; kt < 12; ++kt){
    int k0 = kt * 32;
    short8 a[4];
    #pragma unroll
    for (int mt = 0; mt < 4; ++mt)
      a[mt] = *(const short8*)(smem + a_ao(mt * 16 + l15, k0 + lg * 8));
    #pragma unroll
    for (int nt = 0; nt < 3; ++nt){
      short8 bb = *(const short8*)(wp + (long)np[nt] * 384 + k0 + lg * 8);
      #pragma unroll
      for (int mt = 0; mt < 4; ++mt)
        pacc[mt][nt] = __builtin_amdgcn_mfma_f32_16x16x32_bf16(a[mt], bb, pacc[mt][nt], 0, 0, 0);
    }
  }
  #pragma unroll
  for (int mt = 0; mt < 4; ++mt){
    #pragma unroll
    for (int j = 0; j < 4; ++j){
      int row = mt * 16 + lg * 4 + j;
      if (row < 49){
        float* o = out + ((long)b * 49 + row) * 192;
        #pragma unroll
        for (int nt = 0; nt < 3; ++nt)
          o[np[nt]] = pacc[mt][nt][j] + bp[nt];
      }
    }
  }
}

// ---------------- launch ----------------

extern "C" void kernel_launch(void* const* d_in, const int* in_sizes, int n_in,
                              void* d_out, int out_size, void* d_ws, size_t ws_size,
                              hipStream_t stream){
  (void)in_sizes; (void)n_in; (void)out_size; (void)ws_size;
  const float* x     = (const float*)d_in[0];
  const float* y     = (const float*)d_in[1];
  const float* mask  = (const float*)d_in[2];
  const float* wq_f  = (const float*)d_in[3];
  const float* bqkv  = (const float*)d_in[4];
  const float* wp_f  = (const float*)d_in[5];
  const float* bproj = (const float*)d_in[6];
  const float* btab  = (const float*)d_in[7];

  unsigned short* wq  = (unsigned short*)d_ws;
  unsigned short* wp  = (unsigned short*)((char*)d_ws + WP_OFF);
  float*          cmb = (float*)((char*)d_ws + COMB_OFF);
  float*          out = (float*)d_out;

  hipLaunchKernelGGL(prep_weights, dim3(2016), dim3(256), 0, stream, wq_f, wp_f, wq, wp);
  hipLaunchKernelGGL(prep_comb,    dim3(6144), dim3(256), 0, stream, mask, btab, cmb);
  hipLaunchKernelGGL(fused_attn,   dim3(2048), dim3(256), 0, stream,
                     x, y, bqkv, bproj, wq, wp, cmb, out);
}